// Round 1
// 100.195 us; speedup vs baseline: 1.0314x; 1.0314x over previous
//
#include <hip/hip_runtime.h>
#include <hip/hip_bf16.h>

#define N_NODES 10000
#define E_EDGES 320000
#define D 256
#define LRELU_ALPHA 0.2f

// fp32 world (round 3). dur_us includes ~56 us of harness re-poison fills
// (round-6 forensics). GEMM via mfma_f32_16x16x32_bf16 (round-8 win).
// Round 12: prep kernel deleted — row_start build fused into wprep launch
// (no GEMM dependency), score exp computed lane-parallel in aggregate's
// staging step (a_dst is 40 KB -> L1). Aggregate processes 2 edges per
// vmem instruction (half-wave per edge, ushort8/lane) -> gather instr
// count halved; edata 5.1 MB HBM round-trip removed. 4 launches -> 3.

using short8  = __attribute__((ext_vector_type(8))) short;
using ushort8 = __attribute__((ext_vector_type(8))) unsigned short;
using floatx4 = __attribute__((ext_vector_type(4))) float;
using bf16 = __hip_bfloat16;

__device__ __forceinline__ float bu2f(unsigned short u) {
    return __uint_as_float((unsigned)u << 16);
}
__device__ __forceinline__ unsigned short f2bu(float f) {
    union { bf16 b; unsigned short u; } cv;
    cv.b = __float2bfloat16(f);
    return cv.u;
}

// ---------------------------------------------------------------------------
// K1 (fused): blocks 0..255  -> W1 -> bf16 in MFMA B-fragment order.
//             blocks 256..   -> CSR row_start from sorted src + is64 flag.
// W1f[((s*16+t)*64+l)*8+j] = bf16(W1[k*D+n]), k = s*32+(l>>4)*8+j,
// n = t*16+(l&15). [B layout n=lane&15, k=quad*8+j — m89-verified]
// ---------------------------------------------------------------------------
__global__ __launch_bounds__(256) void prep_fused(const float* __restrict__ W1,
                                                  bf16* __restrict__ W1f,
                                                  const int* __restrict__ raw,
                                                  int* __restrict__ row_start,
                                                  int* __restrict__ flag) {
    const int b = blockIdx.x;
    if (b < 256) {
        const int id = b * 256 + threadIdx.x;  // 65536 exact
        const int j = id & 7, l = (id >> 3) & 63, t = (id >> 9) & 15, s = id >> 13;
        const int k = s * 32 + (l >> 4) * 8 + j;
        const int n = t * 16 + (l & 15);
        W1f[id] = __float2bfloat16(W1[k * D + n]);
        return;
    }
    bool is64 = true;  // int64 rows: [s_lo, s_hi, d_lo, d_hi], hi words == 0
    #pragma unroll
    for (int t = 0; t < 16; ++t)
        if (raw[2 * t + 1] != 0) is64 = false;
    const int e = (b - 256) * 256 + threadIdx.x;
    if (e >= E_EDGES) return;
    if (e == 0) *flag = is64 ? 1 : 0;
    int s, sprev;
    if (is64) { s = raw[4 * e]; sprev = e ? raw[4 * e - 4] : -1; }
    else      { s = raw[2 * e]; sprev = e ? raw[2 * e - 2] : -1; }
    for (int r = sprev + 1; r <= s; ++r) row_start[r] = e;
    if (e == E_EDGES - 1)
        for (int r = s + 1; r <= N_NODES; ++r) row_start[r] = E_EDGES;
}

// ---------------------------------------------------------------------------
// K2: feats = X @ W1 + b1 via v_mfma_f32_16x16x32_bf16, fp32 accumulate.
// X read fp32 and converted to bf16 A-frags inline. 625 blocks x 16 rows.
// Wave w owns cols 64w..64w+63; 32 MFMA/wave. Epilogue: +bias, bf16 feats
// store, fused a_src/a_dst row-dots from fp32 accumulators.
// D layout: col=lane&15, row=quad*4+reg (m89/m91-verified).
// ---------------------------------------------------------------------------
__global__ __launch_bounds__(256) void gemm_mfma(const float* __restrict__ X,
                                                 const bf16* __restrict__ W1f,
                                                 const float* __restrict__ b1,
                                                 const float* __restrict__ Wa,
                                                 bf16* __restrict__ featsb,
                                                 float* __restrict__ a_src,
                                                 float* __restrict__ a_dst) {
    const int w = threadIdx.x >> 6, l = threadIdx.x & 63;
    const int quad = l >> 4, lan = l & 15;
    const int row0 = blockIdx.x * 16;

    floatx4 acc[4] = {{0.f, 0.f, 0.f, 0.f}, {0.f, 0.f, 0.f, 0.f},
                      {0.f, 0.f, 0.f, 0.f}, {0.f, 0.f, 0.f, 0.f}};

    const float4* Ax = (const float4*)(X + (size_t)(row0 + lan) * D);
    const short8* B8 = (const short8*)W1f;

    #pragma unroll
    for (int s = 0; s < 8; ++s) {
        const float4 u = Ax[s * 8 + quad * 2];
        const float4 v = Ax[s * 8 + quad * 2 + 1];
        short8 af;
        af[0] = (short)f2bu(u.x); af[1] = (short)f2bu(u.y);
        af[2] = (short)f2bu(u.z); af[3] = (short)f2bu(u.w);
        af[4] = (short)f2bu(v.x); af[5] = (short)f2bu(v.y);
        af[6] = (short)f2bu(v.z); af[7] = (short)f2bu(v.w);
        #pragma unroll
        for (int t = 0; t < 4; ++t) {
            const short8 bf = B8[(s * 16 + (4 * w + t)) * 64 + l];
            acc[t] = __builtin_amdgcn_mfma_f32_16x16x32_bf16(af, bf, acc[t], 0, 0, 0);
        }
    }

    float p1[4] = {0.f, 0.f, 0.f, 0.f}, p2[4] = {0.f, 0.f, 0.f, 0.f};
    #pragma unroll
    for (int t = 0; t < 4; ++t) {
        const int n = (4 * w + t) * 16 + lan;
        const float bias = b1[n], wa1 = Wa[n], wa2 = Wa[D + n];
        #pragma unroll
        for (int r = 0; r < 4; ++r) {
            const float v = acc[t][r] + bias;
            featsb[(size_t)(row0 + quad * 4 + r) * D + n] = __float2bfloat16(v);
            p1[r] += v * wa1;
            p2[r] += v * wa2;
        }
    }

    __shared__ float red1[4][16], red2[4][16];
    #pragma unroll
    for (int r = 0; r < 4; ++r) {
        #pragma unroll
        for (int off = 1; off < 16; off <<= 1) {
            p1[r] += __shfl_xor(p1[r], off);
            p2[r] += __shfl_xor(p2[r], off);
        }
        if (lan == 0) { red1[w][quad * 4 + r] = p1[r]; red2[w][quad * 4 + r] = p2[r]; }
    }
    __syncthreads();
    if (threadIdx.x < 16) {
        const int m = threadIdx.x;
        a_src[row0 + m] = red1[0][m] + red1[1][m] + red1[2][m] + red1[3][m];
        a_dst[row0 + m] = red2[0][m] + red2[1][m] + red2[2][m] + red2[3][m];
    }
}

// ---------------------------------------------------------------------------
// K3: out[i,:] = (sum_e ex[e] * feats[dst[e],:]) / sum_e ex[e].
// One WAVE per node. Staging step (one edge per LANE): read raw edge,
// gather a_dst[d] (40 KB -> L1), compute x = exp(lrelu(score)) and the
// feats-row byte offset d*512; park (off, x) in wave-private LDS. Main
// loop: TWO edges per vmem instruction — lanes 0..31 own edge 2j (cols
// 8*lh..8*lh+7 via ushort8 = 16 B), lanes 32..63 own edge 2j+1. Even/odd
// fp32 partials merged by one __shfl_xor(...,32) at the end. Same-wave
// LDS is in-order -> no __syncthreads. dsum & scale wave-uniform
// (round-4 lesson).
// ---------------------------------------------------------------------------
__global__ __launch_bounds__(256) void aggregate(const int* __restrict__ raw,
                                                 const int* __restrict__ row_start,
                                                 const int* __restrict__ flag,
                                                 const float* __restrict__ a_src,
                                                 const float* __restrict__ a_dst,
                                                 const float* __restrict__ ba,
                                                 const unsigned short* __restrict__ featsb,
                                                 float* __restrict__ out) {
    __shared__ int2 els[4][64];
    const int wv = threadIdx.x >> 6, l = threadIdx.x & 63;
    const int half = l >> 5, lh = l & 31;
    const int i = blockIdx.x * 4 + wv;  // N_NODES % 4 == 0
    const int rs = row_start[i], re = row_start[i + 1];
    const bool is64 = (*flag) != 0;
    const float base = a_src[i] + ba[0];
    const char* Fbl = (const char*)featsb + lh * 16;

    float acc[8] = {0.f, 0.f, 0.f, 0.f, 0.f, 0.f, 0.f, 0.f};
    float dsum = 0.f;

    for (int e0 = rs; e0 < re; e0 += 64) {
        const int cnt = min(64, re - e0);
        if (l < cnt) {
            const int ee = e0 + l;
            const int d = is64 ? raw[4 * ee + 2] : raw[2 * ee + 1];
            float sc = base + a_dst[d];
            sc = (sc > 0.f) ? sc : LRELU_ALPHA * sc;
            els[wv][l] = make_int2(d << 9, __float_as_int(expf(sc)));
        } else if (l < ((cnt + 1) & ~1)) {
            els[wv][l] = make_int2(0, 0);  // pad: x = 0, row 0 (harmless)
        }
        __builtin_amdgcn_wave_barrier();  // keep write before reads in sched

        const int pairs = (cnt + 1) >> 1;
        int j = 0;
        #define PAIR(idx) do {                                                \
            const int2 ed = els[wv][2 * (idx) + half];                        \
            const ushort8 f = *(const ushort8*)(Fbl + (size_t)(unsigned)ed.x);\
            const float x = __int_as_float(ed.y);                             \
            acc[0] += x * bu2f(f[0]); acc[1] += x * bu2f(f[1]);               \
            acc[2] += x * bu2f(f[2]); acc[3] += x * bu2f(f[3]);               \
            acc[4] += x * bu2f(f[4]); acc[5] += x * bu2f(f[5]);               \
            acc[6] += x * bu2f(f[6]); acc[7] += x * bu2f(f[7]);               \
            dsum += x;                                                        \
        } while (0)
        for (; j + 4 <= pairs; j += 4) {
            PAIR(j); PAIR(j + 1); PAIR(j + 2); PAIR(j + 3);
        }
        for (; j < pairs; ++j) PAIR(j);
        #undef PAIR
        __builtin_amdgcn_wave_barrier();  // next batch's write after reads
    }

    // merge even/odd-edge partials across the half-wave split
    #pragma unroll
    for (int r = 0; r < 8; ++r) acc[r] += __shfl_xor(acc[r], 32);
    dsum += __shfl_xor(dsum, 32);

    const float inv = (re > rs) ? 1.f / dsum : 0.f;  // wave-uniform
    if (l < 32) {
        float4 o0, o1;
        o0.x = acc[0] * inv; o0.y = acc[1] * inv;
        o0.z = acc[2] * inv; o0.w = acc[3] * inv;
        o1.x = acc[4] * inv; o1.y = acc[5] * inv;
        o1.z = acc[6] * inv; o1.w = acc[7] * inv;
        float4* op = (float4*)(out + (size_t)i * D + lh * 8);
        op[0] = o0; op[1] = o1;
    }
}

// ---------------------------------------------------------------------------
extern "C" void kernel_launch(void* const* d_in, const int* in_sizes, int n_in,
                              void* d_out, int out_size, void* d_ws, size_t ws_size,
                              hipStream_t stream) {
    const float* X     = (const float*)d_in[0];
    const int*   edges = (const int*)d_in[1];
    const float* W1    = (const float*)d_in[2];
    const float* b1    = (const float*)d_in[3];
    const float* Wa    = (const float*)d_in[4];
    const float* ba    = (const float*)d_in[5];
    float* out = (float*)d_out;

    // workspace carve-up (~5.4 MB), all 16 B aligned
    bf16* featsb = (bf16*)d_ws;                            // N*D bf16 = 5.12 MB
    bf16* W1f    = featsb + (size_t)N_NODES * D;           // 64K bf16 = 128 KB
    float* a_src = (float*)(W1f + 65536);                  // N
    float* a_dst = a_src + N_NODES;                        // N
    int*   row_start = (int*)(a_dst + N_NODES);            // N+1
    int*   flag  = row_start + N_NODES + 1;                // 1

    prep_fused<<<256 + (E_EDGES + 255) / 256, 256, 0, stream>>>(W1, W1f, edges,
                                                               row_start, flag);
    gemm_mfma<<<N_NODES / 16, 256, 0, stream>>>(X, W1f, b1, Wa, featsb, a_src, a_dst);
    aggregate<<<N_NODES / 4, 256, 0, stream>>>(edges, row_start, flag,
                                               a_src, a_dst, ba,
                                               (const unsigned short*)featsb, out);
}